// Round 8
// baseline (542.688 us; speedup 1.0000x reference)
//
#include <hip/hip_runtime.h>
#include <hip/hip_bf16.h>

// Problem constants
#define BB 2
#define TT 2048
#define CC 1024
#define HH 16
#define DD 64
#define MM (BB * TT)   // 4096 rows

typedef __bf16 bf16;
typedef __bf16 bf16x4 __attribute__((ext_vector_type(4)));
typedef __bf16 bf16x8 __attribute__((ext_vector_type(8)));
typedef float f32x4 __attribute__((ext_vector_type(4)));

// ---------------------------------------------------------------------------
// 8-element fragment loader -> bf16x8 (fp32 variant converts on the fly).
// ---------------------------------------------------------------------------
template <typename T>
__device__ __forceinline__ bf16x8 load8(const T* p);

template <>
__device__ __forceinline__ bf16x8 load8<bf16>(const bf16* p) {
    return *reinterpret_cast<const bf16x8*>(p);
}
template <>
__device__ __forceinline__ bf16x8 load8<float>(const float* p) {
    const f32x4 a = *reinterpret_cast<const f32x4*>(p);
    const f32x4 b = *reinterpret_cast<const f32x4*>(p + 4);
    bf16x8 r;
#pragma unroll
    for (int j = 0; j < 4; ++j) { r[j] = (bf16)a[j]; r[j + 4] = (bf16)b[j]; }
    return r;
}

// ---------------------------------------------------------------------------
// 128x128-tile GEMM body (round-7 PROVEN): Y = X @ W^T + bias, BK=32.
// vmode=1 (V projection): write transposed head layout Vt[B,H,D,T]
// (4 consecutive t per lane -> bf16x4 stores). vmode=0: HEAD_LAYOUT or flat.
// ---------------------------------------------------------------------------
template <typename TX, typename TOUT, int HEAD_LAYOUT>
__device__ __forceinline__ void gemm_tile_body(
    const TX* __restrict__ X, const float* __restrict__ W,
    const float* __restrict__ bias, TOUT* __restrict__ out,
    bf16* lA, bf16* lB, int vmode)
{
    const int tid  = threadIdx.x;
    const int lane = tid & 63;
    const int quad = lane >> 4;
    const int lm   = lane & 15;
    const int wave = tid >> 6;
    const int m0 = blockIdx.x << 7;
    const int n0 = blockIdx.y << 7;
    const int wrow = (wave >> 1) << 6;  // 0 / 64
    const int wcol = (wave & 1) << 6;   // 0 / 64

    const int c0 = tid, c1 = tid + 256;           // 512 chunks per tile
    const TX*    gA0 = X + (size_t)(m0 + (c0 >> 2)) * CC + (c0 & 3) * 8;
    const TX*    gA1 = X + (size_t)(m0 + (c1 >> 2)) * CC + (c1 & 3) * 8;
    const float* gB0 = W + (size_t)(n0 + (c0 >> 2)) * CC + (c0 & 3) * 8;
    const float* gB1 = W + (size_t)(n0 + (c1 >> 2)) * CC + (c1 & 3) * 8;
    bf16* lA0 = lA + c0 * 8;  bf16* lA1 = lA + c1 * 8;
    bf16* lB0 = lB + c0 * 8;  bf16* lB1 = lB + c1 * 8;

    f32x4 acc[4][4];
#pragma unroll
    for (int i = 0; i < 4; ++i)
#pragma unroll
        for (int j = 0; j < 4; ++j) acc[i][j] = (f32x4){0.f, 0.f, 0.f, 0.f};

    for (int kk = 0; kk < CC; kk += 32) {
        bf16x8 a0 = load8<TX>(gA0 + kk);
        bf16x8 a1 = load8<TX>(gA1 + kk);
        bf16x8 b0 = load8<float>(gB0 + kk);
        bf16x8 b1 = load8<float>(gB1 + kk);
        __syncthreads();
        *reinterpret_cast<bf16x8*>(lA0) = a0;
        *reinterpret_cast<bf16x8*>(lA1) = a1;
        *reinterpret_cast<bf16x8*>(lB0) = b0;
        *reinterpret_cast<bf16x8*>(lB1) = b1;
        __syncthreads();

        bf16x8 af[4], bf_[4];
#pragma unroll
        for (int i = 0; i < 4; ++i)
            af[i] = *reinterpret_cast<const bf16x8*>(
                lA + (wrow + i * 16 + lm) * 32 + quad * 8);
#pragma unroll
        for (int j = 0; j < 4; ++j)
            bf_[j] = *reinterpret_cast<const bf16x8*>(
                lB + (wcol + j * 16 + lm) * 32 + quad * 8);
#pragma unroll
        for (int i = 0; i < 4; ++i)
#pragma unroll
            for (int j = 0; j < 4; ++j)
                acc[i][j] = __builtin_amdgcn_mfma_f32_16x16x32_bf16(
                    af[i], bf_[j], acc[i][j], 0, 0, 0);
    }

    // epilogue: C/D layout col = lane&15, row = quad*4 + r
#pragma unroll
    for (int j = 0; j < 4; ++j) {
        const int col = n0 + wcol + j * 16 + lm;
        const float bv = bias[col];
        if (vmode) {  // V^T: out = Vt[B,H,D,T]
            const int h = col / DD, d = col % DD;
#pragma unroll
            for (int i = 0; i < 4; ++i) {
                const int m = m0 + wrow + i * 16 + quad * 4;  // t base
                const int b_ = m / TT, t = m % TT;
                bf16x4 o;
#pragma unroll
                for (int r = 0; r < 4; ++r) o[r] = (bf16)(acc[i][j][r] + bv);
                *reinterpret_cast<bf16x4*>(
                    (bf16*)out + (((size_t)(b_ * HH + h)) * DD + d) * TT + t) = o;
            }
        } else {
#pragma unroll
            for (int i = 0; i < 4; ++i)
#pragma unroll
                for (int r = 0; r < 4; ++r) {
                    const int m = m0 + wrow + i * 16 + quad * 4 + r;
                    const float v = acc[i][j][r] + bv;
                    if (HEAD_LAYOUT) {
                        const int b_ = m / TT, t = m % TT;
                        const int h = col / DD, d = col % DD;
                        out[(((size_t)(b_ * HH + h)) * TT + t) * DD + d] = (TOUT)v;
                    } else {
                        out[(size_t)m * CC + col] = (TOUT)v;
                    }
                }
        }
    }
}

// Fused Q/K/V projections: grid (M/128, C/128, 3); z=2 writes V transposed.
__global__ __launch_bounds__(256) void gemm_qkv(
    const float* __restrict__ x0, const float* __restrict__ x1,
    const float* __restrict__ x2,
    const float* __restrict__ w0, const float* __restrict__ w1,
    const float* __restrict__ w2,
    const float* __restrict__ b0, const float* __restrict__ b1,
    const float* __restrict__ b2,
    bf16* __restrict__ o0, bf16* __restrict__ o1, bf16* __restrict__ o2)
{
    __shared__ __align__(16) bf16 lA[128 * 32];
    __shared__ __align__(16) bf16 lB[128 * 32];
    const int z = blockIdx.z;
    const float* X = (z == 0) ? x0 : (z == 1) ? x1 : x2;
    const float* W = (z == 0) ? w0 : (z == 1) ? w1 : w2;
    const float* bias = (z == 0) ? b0 : (z == 1) ? b1 : b2;
    bf16* out = (z == 0) ? o0 : (z == 1) ? o1 : o2;
    gemm_tile_body<float, bf16, 1>(X, W, bias, out, lA, lB, (z == 2) ? 1 : 0);
}

// Output projection: X = attn ws (bf16 [M,C]), W/bias fp32, out fp32 [M,C].
__global__ __launch_bounds__(256) void gemm_oproj(
    const bf16* __restrict__ X, const float* __restrict__ W,
    const float* __restrict__ bias, float* __restrict__ out)
{
    __shared__ __align__(16) bf16 lA[128 * 32];
    __shared__ __align__(16) bf16 lB[128 * 32];
    gemm_tile_body<bf16, float, 0>(X, W, bias, out, lA, lB, 0);
}

// ---------------------------------------------------------------------------
// Fused causal attention, S^T formulation. NO LDS, NO barriers.
// S^T = K Q^T via mfma(kf, qf): C-layout col = q (lane&15), row = key
// (quad*4+r) -> softmax state is scalar per lane, reductions = 2 shfl_xor.
// PV: O^T[d][q] via mfma(A=V^T-frag from global Vt[B,H,D,T], B=probs
// in-register); contraction order k=quad*8+j <-> s=st(j>>2)*16+quad*4+(j&3)
// applied consistently to both operands.
// Grid: (T/64, B*H). Block: 256 = 4 independent waves; wave owns 16 q rows.
// ---------------------------------------------------------------------------
__global__ __launch_bounds__(256) void attn_fused(
    const bf16* __restrict__ Qh, const bf16* __restrict__ Kh,
    const bf16* __restrict__ Vt, bf16* __restrict__ attn_out)
{
    const int tid  = threadIdx.x;
    const int lane = tid & 63;
    const int wave = tid >> 6;
    const int qb = (TT / 64 - 1) - blockIdx.x;   // longest first
    const int bh = blockIdx.y;
    const int b_ = bh >> 4, h = bh & 15;
    const size_t baseQK = (size_t)bh * TT * DD;  // [T][D]
    const size_t baseVT = (size_t)bh * DD * TT;  // [D][T]
    const int q0 = qb * 64 + wave * 16;
    const int lm   = lane & 15;
    const int quad = lane >> 4;
    const int koff = quad * 8;

    // Q fragment (B-operand: n=q=lm, k=quad*8+j), pre-scaled by 1/8 (exact)
    const bf16* qp = Qh + baseQK + (size_t)(q0 + lm) * DD + koff;
    bf16x8 qr0 = *reinterpret_cast<const bf16x8*>(qp);
    bf16x8 qr1 = *reinterpret_cast<const bf16x8*>(qp + 32);
    bf16x8 qf0, qf1;
#pragma unroll
    for (int j = 0; j < 8; ++j) {
        qf0[j] = (bf16)((float)qr0[j] * 0.125f);
        qf1[j] = (bf16)((float)qr1[j] * 0.125f);
    }

    f32x4 Oacc[4];
#pragma unroll
    for (int dt = 0; dt < 4; ++dt) Oacc[dt] = (f32x4){0.f, 0.f, 0.f, 0.f};
    float m_run = -1e30f, l_run = 0.f;
    const int q_lane = q0 + lm;

    for (int kb = 0; kb <= qb; ++kb) {
        const int s0 = kb * 64;

        // S^T = K Q^T : 4 key-subtiles of 16
        float sv[4][4];
#pragma unroll
        for (int st = 0; st < 4; ++st) {
            const bf16* kp = Kh + baseQK +
                (size_t)(s0 + st * 16 + lm) * DD + koff;
            bf16x8 k0 = *reinterpret_cast<const bf16x8*>(kp);
            bf16x8 k1 = *reinterpret_cast<const bf16x8*>(kp + 32);
            f32x4 s = {0.f, 0.f, 0.f, 0.f};
            s = __builtin_amdgcn_mfma_f32_16x16x32_bf16(k0, qf0, s, 0, 0, 0);
            s = __builtin_amdgcn_mfma_f32_16x16x32_bf16(k1, qf1, s, 0, 0, 0);
            const int kbase = s0 + st * 16 + quad * 4;
#pragma unroll
            for (int r = 0; r < 4; ++r)
                sv[st][r] = (kbase + r <= q_lane) ? s[r] : -1e30f;
        }

        // online softmax: scalar state per lane (q = q0+lm)
        float mx = sv[0][0];
#pragma unroll
        for (int st = 0; st < 4; ++st)
#pragma unroll
            for (int r = 0; r < 4; ++r) mx = fmaxf(mx, sv[st][r]);
        mx = fmaxf(mx, __shfl_xor(mx, 16));
        mx = fmaxf(mx, __shfl_xor(mx, 32));
        const float mn = fmaxf(m_run, mx);
        const float alpha = __expf(m_run - mn);
        m_run = mn;
        float srow = 0.f;
#pragma unroll
        for (int st = 0; st < 4; ++st)
#pragma unroll
            for (int r = 0; r < 4; ++r) {
                const float p = __expf(sv[st][r] - mn);
                sv[st][r] = p;
                srow += p;
            }
        srow += __shfl_xor(srow, 16);
        srow += __shfl_xor(srow, 32);
        l_run = l_run * alpha + srow;
#pragma unroll
        for (int dt = 0; dt < 4; ++dt) Oacc[dt] *= alpha;

        // pack probs -> B-frags (k=quad*8+j <-> s=st*16+quad*4+(j&3))
        bf16x8 pf[2];
#pragma unroll
        for (int c = 0; c < 2; ++c)
#pragma unroll
            for (int j = 0; j < 4; ++j) {
                pf[c][j]     = (bf16)sv[2 * c][j];
                pf[c][4 + j] = (bf16)sv[2 * c + 1][j];
            }

        // O^T += V^T P^T : A-frag = Vt rows (d = dt*16+lm), same s order
#pragma unroll
        for (int dt = 0; dt < 4; ++dt) {
            const bf16* vp = Vt + baseVT +
                (size_t)(dt * 16 + lm) * TT + s0 + quad * 4;
#pragma unroll
            for (int c = 0; c < 2; ++c) {
                bf16x4 v0 = *reinterpret_cast<const bf16x4*>(vp + c * 32);
                bf16x4 v1 = *reinterpret_cast<const bf16x4*>(vp + c * 32 + 16);
                bf16x8 vf;
#pragma unroll
                for (int j = 0; j < 4; ++j) { vf[j] = v0[j]; vf[4 + j] = v1[j]; }
                Oacc[dt] = __builtin_amdgcn_mfma_f32_16x16x32_bf16(
                    vf, pf[c], Oacc[dt], 0, 0, 0);
            }
        }
    }

    // epilogue: O = O^T(col q=lm, row d=quad*4+r) / l, write [M,C] bf16
    const float inv_l = 1.0f / l_run;
    bf16* dst = attn_out + ((size_t)(b_ * TT + q_lane)) * CC + h * DD;
#pragma unroll
    for (int dt = 0; dt < 4; ++dt) {
        bf16x4 o;
#pragma unroll
        for (int r = 0; r < 4; ++r) o[r] = (bf16)(Oacc[dt][r] * inv_l);
        *reinterpret_cast<bf16x4*>(dst + dt * 16 + quad * 4) = o;
    }
}

// ---------------------------------------------------------------------------
extern "C" void kernel_launch(void* const* d_in, const int* in_sizes, int n_in,
                              void* d_out, int out_size, void* d_ws,
                              size_t ws_size, hipStream_t stream)
{
    const float* q  = (const float*)d_in[0];
    const float* k  = (const float*)d_in[1];
    const float* v  = (const float*)d_in[2];
    const float* Wq = (const float*)d_in[4];
    const float* bq = (const float*)d_in[5];
    const float* Wk = (const float*)d_in[6];
    const float* bk = (const float*)d_in[7];
    const float* Wv = (const float*)d_in[8];
    const float* bv = (const float*)d_in[9];
    const float* Wo = (const float*)d_in[10];
    const float* bo = (const float*)d_in[11];
    float* out = (float*)d_out;            // fp32 output [M, C]

    // workspace: Qh [B,H,T,D] | Kh [B,H,T,D] | Vt [B,H,D,T] | attn [M,C]
    bf16* Qh = (bf16*)d_ws;
    bf16* Kh = Qh + (size_t)MM * CC;
    bf16* Vt = Kh + (size_t)MM * CC;
    bf16* attn = Vt + (size_t)MM * CC;

    const dim3 blk(256);
    gemm_qkv<<<dim3(MM / 128, CC / 128, 3), blk, 0, stream>>>(
        q, k, v, Wq, Wk, Wv, bq, bk, bv, Qh, Kh, Vt);
    attn_fused<<<dim3(TT / 64, BB * HH), blk, 0, stream>>>(Qh, Kh, Vt, attn);
    gemm_oproj<<<dim3(MM / 128, CC / 128), blk, 0, stream>>>(
        attn, Wo, bo, out);
}

// Round 9
// 292.537 us; speedup vs baseline: 1.8551x; 1.8551x over previous
//
#include <hip/hip_runtime.h>
#include <hip/hip_bf16.h>

// Problem constants
#define BB 2
#define TT 2048
#define CC 1024
#define HH 16
#define DD 64
#define MM (BB * TT)   // 4096 rows

typedef __bf16 bf16;
typedef __bf16 bf16x4 __attribute__((ext_vector_type(4)));
typedef __bf16 bf16x8 __attribute__((ext_vector_type(8)));
typedef float f32x4 __attribute__((ext_vector_type(4)));

// ---------------------------------------------------------------------------
// 8-element fragment loader -> bf16x8 (fp32 variant converts on the fly).
// ---------------------------------------------------------------------------
template <typename T>
__device__ __forceinline__ bf16x8 load8(const T* p);

template <>
__device__ __forceinline__ bf16x8 load8<bf16>(const bf16* p) {
    return *reinterpret_cast<const bf16x8*>(p);
}
template <>
__device__ __forceinline__ bf16x8 load8<float>(const float* p) {
    const f32x4 a = *reinterpret_cast<const f32x4*>(p);
    const f32x4 b = *reinterpret_cast<const f32x4*>(p + 4);
    bf16x8 r;
#pragma unroll
    for (int j = 0; j < 4; ++j) { r[j] = (bf16)a[j]; r[j + 4] = (bf16)b[j]; }
    return r;
}

// ---------------------------------------------------------------------------
// 128x128-tile GEMM body (PROVEN r7/r8): Y = X @ W^T + bias, BK=32.
// vmode=1 (V projection): write transposed head layout Vt[B,H,D,T].
// ---------------------------------------------------------------------------
template <typename TX, typename TOUT, int HEAD_LAYOUT>
__device__ __forceinline__ void gemm_tile_body(
    const TX* __restrict__ X, const float* __restrict__ W,
    const float* __restrict__ bias, TOUT* __restrict__ out,
    bf16* lA, bf16* lB, int vmode)
{
    const int tid  = threadIdx.x;
    const int lane = tid & 63;
    const int quad = lane >> 4;
    const int lm   = lane & 15;
    const int wave = tid >> 6;
    const int m0 = blockIdx.x << 7;
    const int n0 = blockIdx.y << 7;
    const int wrow = (wave >> 1) << 6;  // 0 / 64
    const int wcol = (wave & 1) << 6;   // 0 / 64

    const int c0 = tid, c1 = tid + 256;           // 512 chunks per tile
    const TX*    gA0 = X + (size_t)(m0 + (c0 >> 2)) * CC + (c0 & 3) * 8;
    const TX*    gA1 = X + (size_t)(m0 + (c1 >> 2)) * CC + (c1 & 3) * 8;
    const float* gB0 = W + (size_t)(n0 + (c0 >> 2)) * CC + (c0 & 3) * 8;
    const float* gB1 = W + (size_t)(n0 + (c1 >> 2)) * CC + (c1 & 3) * 8;
    bf16* lA0 = lA + c0 * 8;  bf16* lA1 = lA + c1 * 8;
    bf16* lB0 = lB + c0 * 8;  bf16* lB1 = lB + c1 * 8;

    f32x4 acc[4][4];
#pragma unroll
    for (int i = 0; i < 4; ++i)
#pragma unroll
        for (int j = 0; j < 4; ++j) acc[i][j] = (f32x4){0.f, 0.f, 0.f, 0.f};

    for (int kk = 0; kk < CC; kk += 32) {
        bf16x8 a0 = load8<TX>(gA0 + kk);
        bf16x8 a1 = load8<TX>(gA1 + kk);
        bf16x8 b0 = load8<float>(gB0 + kk);
        bf16x8 b1 = load8<float>(gB1 + kk);
        __syncthreads();
        *reinterpret_cast<bf16x8*>(lA0) = a0;
        *reinterpret_cast<bf16x8*>(lA1) = a1;
        *reinterpret_cast<bf16x8*>(lB0) = b0;
        *reinterpret_cast<bf16x8*>(lB1) = b1;
        __syncthreads();

        bf16x8 af[4], bf_[4];
#pragma unroll
        for (int i = 0; i < 4; ++i)
            af[i] = *reinterpret_cast<const bf16x8*>(
                lA + (wrow + i * 16 + lm) * 32 + quad * 8);
#pragma unroll
        for (int j = 0; j < 4; ++j)
            bf_[j] = *reinterpret_cast<const bf16x8*>(
                lB + (wcol + j * 16 + lm) * 32 + quad * 8);
#pragma unroll
        for (int i = 0; i < 4; ++i)
#pragma unroll
            for (int j = 0; j < 4; ++j)
                acc[i][j] = __builtin_amdgcn_mfma_f32_16x16x32_bf16(
                    af[i], bf_[j], acc[i][j], 0, 0, 0);
    }

    // epilogue: C/D layout col = lane&15, row = quad*4 + r
#pragma unroll
    for (int j = 0; j < 4; ++j) {
        const int col = n0 + wcol + j * 16 + lm;
        const float bv = bias[col];
        if (vmode) {  // V^T: out = Vt[B,H,D,T]
            const int h = col / DD, d = col % DD;
#pragma unroll
            for (int i = 0; i < 4; ++i) {
                const int m = m0 + wrow + i * 16 + quad * 4;  // t base
                const int b_ = m / TT, t = m % TT;
                bf16x4 o;
#pragma unroll
                for (int r = 0; r < 4; ++r) o[r] = (bf16)(acc[i][j][r] + bv);
                *reinterpret_cast<bf16x4*>(
                    (bf16*)out + (((size_t)(b_ * HH + h)) * DD + d) * TT + t) = o;
            }
        } else {
#pragma unroll
            for (int i = 0; i < 4; ++i)
#pragma unroll
                for (int r = 0; r < 4; ++r) {
                    const int m = m0 + wrow + i * 16 + quad * 4 + r;
                    const float v = acc[i][j][r] + bv;
                    if (HEAD_LAYOUT) {
                        const int b_ = m / TT, t = m % TT;
                        const int h = col / DD, d = col % DD;
                        out[(((size_t)(b_ * HH + h)) * TT + t) * DD + d] = (TOUT)v;
                    } else {
                        out[(size_t)m * CC + col] = (TOUT)v;
                    }
                }
        }
    }
}

// Fused Q/K/V projections: grid (M/128, C/128, 3); z=2 writes V transposed.
__global__ __launch_bounds__(256) void gemm_qkv(
    const float* __restrict__ x0, const float* __restrict__ x1,
    const float* __restrict__ x2,
    const float* __restrict__ w0, const float* __restrict__ w1,
    const float* __restrict__ w2,
    const float* __restrict__ b0, const float* __restrict__ b1,
    const float* __restrict__ b2,
    bf16* __restrict__ o0, bf16* __restrict__ o1, bf16* __restrict__ o2)
{
    __shared__ __align__(16) bf16 lA[128 * 32];
    __shared__ __align__(16) bf16 lB[128 * 32];
    const int z = blockIdx.z;
    const float* X = (z == 0) ? x0 : (z == 1) ? x1 : x2;
    const float* W = (z == 0) ? w0 : (z == 1) ? w1 : w2;
    const float* bias = (z == 0) ? b0 : (z == 1) ? b1 : b2;
    bf16* out = (z == 0) ? o0 : (z == 1) ? o1 : o2;
    gemm_tile_body<float, bf16, 1>(X, W, bias, out, lA, lB, (z == 2) ? 1 : 0);
}

// Output projection: X = attn ws (bf16 [M,C]), W/bias fp32, out fp32 [M,C].
__global__ __launch_bounds__(256) void gemm_oproj(
    const bf16* __restrict__ X, const float* __restrict__ W,
    const float* __restrict__ bias, float* __restrict__ out)
{
    __shared__ __align__(16) bf16 lA[128 * 32];
    __shared__ __align__(16) bf16 lB[128 * 32];
    gemm_tile_body<bf16, float, 0>(X, W, bias, out, lA, lB, 0);
}

// ---------------------------------------------------------------------------
// Fused causal attention, S^T formulation (r8 math, PROVEN) with LDS-staged
// K and V tiles (fixes r8's uncoalesced per-lane V gather).
//   ldsK [key][72]  : b128 reads/writes at the 8-pass floor; global coalesced
//   ldsV [g][d][4]  : g = s>>2; cell (g,d) = V^T[d][4g..4g+3]; b64 reads at
//                     the 4-pass floor (bank = 2*lm mod 32, 4 quads/window)
// Softmax state scalar per lane (col = q = lane&15); probs stay in registers
// and feed PV's B-operand directly (no ldsP roundtrip, no butterflies).
// Grid: (T/64, B*H). Block: 256 = 4 waves; wave owns 16 q rows.
// ---------------------------------------------------------------------------
__global__ __launch_bounds__(256) void attn_fused(
    const bf16* __restrict__ Qh, const bf16* __restrict__ Kh,
    const bf16* __restrict__ Vt, bf16* __restrict__ attn_out)
{
    __shared__ __align__(16) bf16 ldsK[64 * 72];       // 9216 B
    __shared__ __align__(16) bf16 ldsV[16 * 64 * 4];   // 8192 B

    const int tid  = threadIdx.x;
    const int lane = tid & 63;
    const int wave = tid >> 6;
    const int qb = (TT / 64 - 1) - blockIdx.x;   // longest first
    const int bh = blockIdx.y;
    const int b_ = bh >> 4, h = bh & 15;
    const size_t baseQK = (size_t)bh * TT * DD;  // [T][D]
    const size_t baseVT = (size_t)bh * DD * TT;  // [D][T]
    const int q0 = qb * 64 + wave * 16;
    const int lm   = lane & 15;
    const int quad = lane >> 4;
    const int koff = quad * 8;

    // staging indices
    const int kKey = tid >> 3, kDc = tid & 7;    // K: key row, 16-B chunk
    const int vD   = tid >> 2, vSc = tid & 3;    // V: d row, 16-B s-chunk

    // Q fragment (B-operand: n=q=lm, k=quad*8+j), pre-scaled by 1/8 (exact)
    const bf16* qp = Qh + baseQK + (size_t)(q0 + lm) * DD + koff;
    bf16x8 qr0 = *reinterpret_cast<const bf16x8*>(qp);
    bf16x8 qr1 = *reinterpret_cast<const bf16x8*>(qp + 32);
    bf16x8 qf0, qf1;
#pragma unroll
    for (int j = 0; j < 8; ++j) {
        qf0[j] = (bf16)((float)qr0[j] * 0.125f);
        qf1[j] = (bf16)((float)qr1[j] * 0.125f);
    }

    f32x4 Oacc[4];
#pragma unroll
    for (int dt = 0; dt < 4; ++dt) Oacc[dt] = (f32x4){0.f, 0.f, 0.f, 0.f};
    float m_run = -1e30f, l_run = 0.f;
    const int q_lane = q0 + lm;

    for (int kb = 0; kb <= qb; ++kb) {
        const int s0 = kb * 64;

        __syncthreads();                 // previous tile's readers done
        // stage K tile (64 keys x 64 d), coalesced; floor-conflict writes
#pragma unroll
        for (int it = 0; it < 2; ++it) {
            const int key = kKey + it * 32;
            bf16x8 kv = *reinterpret_cast<const bf16x8*>(
                Kh + baseQK + (size_t)(s0 + key) * DD + kDc * 8);
            *reinterpret_cast<bf16x8*>(&ldsK[key * 72 + kDc * 8]) = kv;
        }
        // stage V tile: Vt rows d, s-chunks of 8 -> cells (g=2sc+h, d)
#pragma unroll
        for (int it = 0; it < 2; ++it) {
            const int sc = vSc + it * 4;
            bf16x8 vv = *reinterpret_cast<const bf16x8*>(
                Vt + baseVT + (size_t)vD * TT + s0 + sc * 8);
            bf16x4 lo, hi;
#pragma unroll
            for (int j = 0; j < 4; ++j) { lo[j] = vv[j]; hi[j] = vv[4 + j]; }
            *reinterpret_cast<bf16x4*>(&ldsV[((2 * sc) * 64 + vD) * 4]) = lo;
            *reinterpret_cast<bf16x4*>(&ldsV[((2 * sc + 1) * 64 + vD) * 4]) = hi;
        }
        __syncthreads();                 // tiles visible

        if (s0 > q0 + 15) continue;      // fully masked for this wave (uniform)

        // S^T = K Q^T : 4 key-subtiles of 16
        float sv[4][4];
#pragma unroll
        for (int st = 0; st < 4; ++st) {
            const bf16* kp = &ldsK[(st * 16 + lm) * 72 + koff];
            bf16x8 k0 = *reinterpret_cast<const bf16x8*>(kp);
            bf16x8 k1 = *reinterpret_cast<const bf16x8*>(kp + 32);
            f32x4 s = {0.f, 0.f, 0.f, 0.f};
            s = __builtin_amdgcn_mfma_f32_16x16x32_bf16(k0, qf0, s, 0, 0, 0);
            s = __builtin_amdgcn_mfma_f32_16x16x32_bf16(k1, qf1, s, 0, 0, 0);
            const int kbase = s0 + st * 16 + quad * 4;
#pragma unroll
            for (int r = 0; r < 4; ++r)
                sv[st][r] = (kbase + r <= q_lane) ? s[r] : -1e30f;
        }

        // online softmax: scalar state per lane (q = q0+lm)
        float mx = sv[0][0];
#pragma unroll
        for (int st = 0; st < 4; ++st)
#pragma unroll
            for (int r = 0; r < 4; ++r) mx = fmaxf(mx, sv[st][r]);
        mx = fmaxf(mx, __shfl_xor(mx, 16));
        mx = fmaxf(mx, __shfl_xor(mx, 32));
        const float mn = fmaxf(m_run, mx);
        const float alpha = __expf(m_run - mn);
        m_run = mn;
        float srow = 0.f;
#pragma unroll
        for (int st = 0; st < 4; ++st)
#pragma unroll
            for (int r = 0; r < 4; ++r) {
                const float p = __expf(sv[st][r] - mn);
                sv[st][r] = p;
                srow += p;
            }
        srow += __shfl_xor(srow, 16);
        srow += __shfl_xor(srow, 32);
        l_run = l_run * alpha + srow;
#pragma unroll
        for (int dt = 0; dt < 4; ++dt) Oacc[dt] *= alpha;

        // pack probs -> B-frags (k=quad*8+j <-> s = c*32 + (j>>2)*16 + quad*4 + (j&3))
        bf16x8 pf[2];
#pragma unroll
        for (int c = 0; c < 2; ++c)
#pragma unroll
            for (int j = 0; j < 4; ++j) {
                pf[c][j]     = (bf16)sv[2 * c][j];
                pf[c][4 + j] = (bf16)sv[2 * c + 1][j];
            }

        // O^T += V^T P^T : A-frag from ldsV cells (g = c*8 + {0,4} + quad, d)
#pragma unroll
        for (int dt = 0; dt < 4; ++dt) {
            const int d = dt * 16 + lm;
#pragma unroll
            for (int c = 0; c < 2; ++c) {
                bf16x4 v0 = *reinterpret_cast<const bf16x4*>(
                    &ldsV[((c * 8 + quad) * 64 + d) * 4]);
                bf16x4 v1 = *reinterpret_cast<const bf16x4*>(
                    &ldsV[((c * 8 + 4 + quad) * 64 + d) * 4]);
                bf16x8 vf;
#pragma unroll
                for (int j = 0; j < 4; ++j) { vf[j] = v0[j]; vf[4 + j] = v1[j]; }
                Oacc[dt] = __builtin_amdgcn_mfma_f32_16x16x32_bf16(
                    vf, pf[c], Oacc[dt], 0, 0, 0);
            }
        }
    }

    // epilogue: O = O^T(col q=lm, row d=quad*4+r) / l, write [M,C] bf16
    const float inv_l = 1.0f / l_run;
    bf16* dst = attn_out + ((size_t)(b_ * TT + q_lane)) * CC + h * DD;
#pragma unroll
    for (int dt = 0; dt < 4; ++dt) {
        bf16x4 o;
#pragma unroll
        for (int r = 0; r < 4; ++r) o[r] = (bf16)(Oacc[dt][r] * inv_l);
        *reinterpret_cast<bf16x4*>(dst + dt * 16 + quad * 4) = o;
    }
}

// ---------------------------------------------------------------------------
extern "C" void kernel_launch(void* const* d_in, const int* in_sizes, int n_in,
                              void* d_out, int out_size, void* d_ws,
                              size_t ws_size, hipStream_t stream)
{
    const float* q  = (const float*)d_in[0];
    const float* k  = (const float*)d_in[1];
    const float* v  = (const float*)d_in[2];
    const float* Wq = (const float*)d_in[4];
    const float* bq = (const float*)d_in[5];
    const float* Wk = (const float*)d_in[6];
    const float* bk = (const float*)d_in[7];
    const float* Wv = (const float*)d_in[8];
    const float* bv = (const float*)d_in[9];
    const float* Wo = (const float*)d_in[10];
    const float* bo = (const float*)d_in[11];
    float* out = (float*)d_out;            // fp32 output [M, C]

    // workspace: Qh [B,H,T,D] | Kh [B,H,T,D] | Vt [B,H,D,T] | attn [M,C]
    bf16* Qh = (bf16*)d_ws;
    bf16* Kh = Qh + (size_t)MM * CC;
    bf16* Vt = Kh + (size_t)MM * CC;
    bf16* attn = Vt + (size_t)MM * CC;

    const dim3 blk(256);
    gemm_qkv<<<dim3(MM / 128, CC / 128, 3), blk, 0, stream>>>(
        q, k, v, Wq, Wk, Wv, bq, bk, bv, Qh, Kh, Vt);
    attn_fused<<<dim3(TT / 64, BB * HH), blk, 0, stream>>>(Qh, Kh, Vt, attn);
    gemm_oproj<<<dim3(MM / 128, CC / 128), blk, 0, stream>>>(
        attn, Wo, bo, out);
}